// Round 1
// baseline (440.792 us; speedup 1.0000x reference)
//
#include <hip/hip_runtime.h>
#include <stdint.h>

// ============================================================================
// MultiHeadAttention fused pipeline (MI355X / gfx950)
//   B=2, S=2048, D=1024, H=16, DEPTH=64
//   out0: out [B,S,D] f32 (4194304), out1: weights [B,H,S,S] f32 (134217728)
// Pipeline:
//   k0a: convert Q,K,V f32 -> f16        (ws)
//   k0b: transpose+convert w* -> [N,K]f16 (ws)
//   k1 : 128x128 f16 MFMA GEMM -> qh[B,H,S,64], kh[B,H,S,64], vT[B,H,64,S]
//   k2 : fused attention: scores(regs) -> softmax -> weights(HBM f32 + LDS f16)
//        -> PV (swapped, via swizzled LDS) -> concat [B*S,1024] f16
//   k3 : out = concat @ woT + bo -> f32
// ============================================================================

typedef _Float16 half8 __attribute__((ext_vector_type(8)));
typedef float f32x4 __attribute__((ext_vector_type(4)));

#define MFMA16(a, b, c) __builtin_amdgcn_mfma_f32_16x16x32_f16((a), (b), (c), 0, 0, 0)

__device__ __forceinline__ void load_lds16(const void* g, void* l) {
  __builtin_amdgcn_global_load_lds(
      (const __attribute__((address_space(1))) void*)(uintptr_t)g,
      (__attribute__((address_space(3))) void*)(uintptr_t)l, 16, 0, 0);
}

// ---------------------------------------------------------------------------
// k0a: f32 -> f16 convert, 8 elems/thread
// ---------------------------------------------------------------------------
__global__ __launch_bounds__(256) void cvt_f16_kernel(
    const float* __restrict__ in, _Float16* __restrict__ out, int n8) {
  int i = blockIdx.x * blockDim.x + threadIdx.x;
  if (i >= n8) return;
  const float4* p = (const float4*)in + 2 * (size_t)i;
  float4 a = p[0], b = p[1];
  half8 h;
  h[0] = (_Float16)a.x; h[1] = (_Float16)a.y; h[2] = (_Float16)a.z; h[3] = (_Float16)a.w;
  h[4] = (_Float16)b.x; h[5] = (_Float16)b.y; h[6] = (_Float16)b.z; h[7] = (_Float16)b.w;
  *((half8*)out + i) = h;
}

// ---------------------------------------------------------------------------
// k0b: w [1024x1024] f32 -> wT [1024x1024] f16  (wT[n][k] = w[k][n])
// grid (16,16), block 256. 64x64 tiles via LDS.
// ---------------------------------------------------------------------------
__global__ __launch_bounds__(256) void transpose_cvt_kernel(
    const float* __restrict__ in, _Float16* __restrict__ out) {
  __shared__ _Float16 tile[64][72];  // pad to dodge bank conflicts
  const int r  = threadIdx.x >> 2;   // 0..63
  const int c4 = threadIdx.x & 3;    // 0..3 (16 cols each)
  const int kin = blockIdx.y * 64, nin = blockIdx.x * 64;
#pragma unroll
  for (int i = 0; i < 4; ++i) {
    float4 v = *(const float4*)(in + (size_t)(kin + r) * 1024 + nin + c4 * 16 + i * 4);
    tile[c4 * 16 + i * 4 + 0][r] = (_Float16)v.x;
    tile[c4 * 16 + i * 4 + 1][r] = (_Float16)v.y;
    tile[c4 * 16 + i * 4 + 2][r] = (_Float16)v.z;
    tile[c4 * 16 + i * 4 + 3][r] = (_Float16)v.w;
  }
  __syncthreads();
#pragma unroll
  for (int i = 0; i < 4; ++i) {
    union { _Float16 hh[4]; uint2 u; } p;
    p.hh[0] = tile[r][c4 * 16 + i * 4 + 0];
    p.hh[1] = tile[r][c4 * 16 + i * 4 + 1];
    p.hh[2] = tile[r][c4 * 16 + i * 4 + 2];
    p.hh[3] = tile[r][c4 * 16 + i * 4 + 3];
    *(uint2*)(out + (size_t)(nin + r) * 1024 + kin + c4 * 16 + i * 4) = p.u;
  }
}

// ---------------------------------------------------------------------------
// k1/k3: 128x128-tile f16 GEMM, 4 waves, BK=32, global_load_lds staging,
// XOR slot swizzle (2-way-free ds_read_b128 frag reads).
//   A  [M x K] f16 row-major,  BT [N x K] f16 row-major (B transposed), N=1024
// MODE 0: out = qh/kh layout [B,H,S,64] f16    (m=token, n=h*64+d)
// MODE 1: out = vT layout    [B,H,64,S] f16
// MODE 2: out = plain f32 [M x 1024]
// grid (N/128=8, M/128=32), block 256
// ---------------------------------------------------------------------------
template <int MODE>
__global__ __launch_bounds__(256, 2) void gemm_f16_kernel(
    const _Float16* __restrict__ A, const _Float16* __restrict__ BT,
    const float* __restrict__ bias, void* __restrict__ out, int K) {
  __shared__ __align__(16) _Float16 As[128 * 32];
  __shared__ __align__(16) _Float16 Bs[128 * 32];
  const int tid = threadIdx.x;
  const int w = tid >> 6, l = tid & 63;
  const int g = l >> 4, c = l & 15;
  const int tm = blockIdx.y * 128, tn = blockIdx.x * 128;
  const int wr = w >> 1, wc = w & 1;  // wave -> 64x64 quadrant

  f32x4 acc[4][4];
#pragma unroll
  for (int i = 0; i < 4; ++i)
#pragma unroll
    for (int j = 0; j < 4; ++j) acc[i][j] = (f32x4){0.f, 0.f, 0.f, 0.f};

  const int srow0 = w * 16 + (l >> 2);  // row within 64-row round
  const int sl = l & 3;                 // 16B slot within 64B row

  for (int kt = 0; kt < K; kt += 32) {
#pragma unroll
    for (int r = 0; r < 2; ++r) {
      const int row = r * 64 + srow0;
      const int kc = sl ^ ((row >> 1) & 3);  // swizzled source chunk
      load_lds16(A + (size_t)(tm + row) * K + kt + kc * 8, As + row * 32 + sl * 8);
      load_lds16(BT + (size_t)(tn + row) * K + kt + kc * 8, Bs + row * 32 + sl * 8);
    }
    __syncthreads();
    half8 af[4], bf[4];
#pragma unroll
    for (int mt = 0; mt < 4; ++mt) {
      const int row = wr * 64 + mt * 16 + c;
      af[mt] = *(const half8*)(As + row * 32 + (g ^ ((row >> 1) & 3)) * 8);
    }
#pragma unroll
    for (int nt = 0; nt < 4; ++nt) {
      const int row = wc * 64 + nt * 16 + c;
      bf[nt] = *(const half8*)(Bs + row * 32 + (g ^ ((row >> 1) & 3)) * 8);
    }
#pragma unroll
    for (int mt = 0; mt < 4; ++mt)
#pragma unroll
      for (int nt = 0; nt < 4; ++nt)
        acc[mt][nt] = MFMA16(af[mt], bf[nt], acc[mt][nt]);
    __syncthreads();
  }

  // epilogue: D mapping col=lane&15, row=4*(lane>>4)+r
#pragma unroll
  for (int mt = 0; mt < 4; ++mt) {
#pragma unroll
    for (int nt = 0; nt < 4; ++nt) {
      const int n = tn + wc * 64 + nt * 16 + c;
      const float bv = bias[n];
      if (MODE == 2) {
#pragma unroll
        for (int r = 0; r < 4; ++r) {
          const int m = tm + wr * 64 + mt * 16 + 4 * g + r;
          ((float*)out)[(size_t)m * 1024 + n] = acc[mt][nt][r] + bv;
        }
      } else if (MODE == 0) {
        const int h_ = n >> 6, d_ = n & 63;
#pragma unroll
        for (int r = 0; r < 4; ++r) {
          const int m = tm + wr * 64 + mt * 16 + 4 * g + r;
          const int b_ = m >> 11, s_ = m & 2047;
          ((_Float16*)out)[((size_t)(b_ * 16 + h_) * 2048 + s_) * 64 + d_] =
              (_Float16)(acc[mt][nt][r] + bv);
        }
      } else {  // MODE 1: vT [B,H,64,S], pack 4 consecutive s per lane
        const int h_ = n >> 6, d_ = n & 63;
        const int m0 = tm + wr * 64 + mt * 16 + 4 * g;
        const int b_ = m0 >> 11, s0 = m0 & 2047;
        union { _Float16 hh[4]; uint2 u; } p;
#pragma unroll
        for (int r = 0; r < 4; ++r) p.hh[r] = (_Float16)(acc[mt][nt][r] + bv);
        *(uint2*)((_Float16*)out + ((size_t)(b_ * 16 + h_) * 64 + d_) * 2048 + s0) = p.u;
      }
    }
  }
}

// ---------------------------------------------------------------------------
// k2: fused attention. Block = (b,h,qtile of 16 rows), 4 waves.
// Wave w owns k-cols [w*512, (w+1)*512). Full score row-block in registers.
// ---------------------------------------------------------------------------
__global__ __launch_bounds__(256, 2) void attn_kernel(
    const _Float16* __restrict__ qh,   // [BH, S, 64]
    const _Float16* __restrict__ kh,   // [BH, S, 64]
    const _Float16* __restrict__ vT,   // [BH, 64, S]
    float* __restrict__ wout,          // [BH, S, S]
    _Float16* __restrict__ concat) {   // [B*S, 1024]
  __shared__ __align__(16) char smem[65536];  // W f16 [16][2048] swizzled; red + PV partials alias
  const int tid = threadIdx.x;
  const int w = tid >> 6, l = tid & 63;
  const int g = l >> 4, c = l & 15;
  const int qt = blockIdx.x, h = blockIdx.y, b = blockIdx.z;
  const int bh = b * 16 + h;
  const _Float16* qp = qh + (size_t)bh * 2048 * 64;
  const _Float16* kp = kh + (size_t)bh * 2048 * 64;
  const _Float16* vp = vT + (size_t)bh * 64 * 2048;
  const int q0 = qt * 16;
  const int kbase = w * 512;

  // --- Phase A: Q fragments (A-frag: m=lane&15, k=8*(lane>>4)+j) ---
  const half8 aq0 = *(const half8*)(qp + (size_t)(q0 + c) * 64 + 8 * g);
  const half8 aq1 = *(const half8*)(qp + (size_t)(q0 + c) * 64 + 32 + 8 * g);

  // --- Phase B: QK^T -> sc[t][r] = S[q0+4g+r][kbase+t*16+c] * 1/8 ---
  f32x4 sc[32];
#pragma unroll
  for (int t = 0; t < 32; ++t) {
    const _Float16* kr = kp + (size_t)(kbase + t * 16 + c) * 64 + 8 * g;
    half8 b0 = *(const half8*)(kr);
    half8 b1 = *(const half8*)(kr + 32);
    f32x4 s = (f32x4){0.f, 0.f, 0.f, 0.f};
    s = MFMA16(aq0, b0, s);
    s = MFMA16(aq1, b1, s);
    sc[t] = s * 0.125f;
  }

  // --- Phase C: exact softmax (16-lane shfl + cross-wave LDS) ---
  float* red0 = (float*)smem;        // [4 waves][16 rows]
  float* red1 = (float*)smem + 64;   // [4 waves][16 rows]
  float m4[4], sum4[4], inv4[4];
#pragma unroll
  for (int r = 0; r < 4; ++r) {
    float mx = sc[0][r];
#pragma unroll
    for (int t = 1; t < 32; ++t) mx = fmaxf(mx, sc[t][r]);
#pragma unroll
    for (int d = 1; d < 16; d <<= 1) mx = fmaxf(mx, __shfl_xor(mx, d, 64));
    m4[r] = mx;
  }
  if (c == 0) {
#pragma unroll
    for (int r = 0; r < 4; ++r) red0[w * 16 + 4 * g + r] = m4[r];
  }
  __syncthreads();
#pragma unroll
  for (int r = 0; r < 4; ++r) {
    float mx = red0[4 * g + r];
#pragma unroll
    for (int ww = 1; ww < 4; ++ww) mx = fmaxf(mx, red0[ww * 16 + 4 * g + r]);
    m4[r] = mx;
    sum4[r] = 0.f;
  }
#pragma unroll
  for (int t = 0; t < 32; ++t) {
#pragma unroll
    for (int r = 0; r < 4; ++r) {
      float e = __expf(sc[t][r] - m4[r]);
      sc[t][r] = e;
      sum4[r] += e;
    }
  }
#pragma unroll
  for (int r = 0; r < 4; ++r) {
    float s = sum4[r];
#pragma unroll
    for (int d = 1; d < 16; d <<= 1) s += __shfl_xor(s, d, 64);
    sum4[r] = s;
  }
  if (c == 0) {
#pragma unroll
    for (int r = 0; r < 4; ++r) red1[w * 16 + 4 * g + r] = sum4[r];
  }
  __syncthreads();
#pragma unroll
  for (int r = 0; r < 4; ++r) {
    float s = red1[4 * g + r] + red1[16 + 4 * g + r] + red1[32 + 4 * g + r] +
              red1[48 + 4 * g + r];
    inv4[r] = 1.0f / s;
  }
  __syncthreads();  // protect red region before W LDS writes overwrite it

  // --- Phase D: weights -> HBM (f32) and LDS (f16, XOR-swizzled rows) ---
  float* wrow = wout + ((size_t)bh * 2048 + q0) * 2048 + kbase;
#pragma unroll
  for (int t = 0; t < 32; ++t) {
#pragma unroll
    for (int r = 0; r < 4; ++r) {
      const int row = 4 * g + r;
      const float val = sc[t][r] * inv4[r];
      wrow[(size_t)row * 2048 + t * 16 + c] = val;
      const int colb = (kbase + t * 16 + c) * 2;
      *(_Float16*)(smem + row * 4096 + (colb ^ ((row & 7) << 4))) = (_Float16)val;
    }
  }

  // --- Phase E: PV swapped: attnT[d][q] = sum_k vT[d][k] * W[q][k] ---
  // (wave reads only its own W slice -> no barrier needed after D)
  f32x4 pv[4];
#pragma unroll
  for (int dt = 0; dt < 4; ++dt) pv[dt] = (f32x4){0.f, 0.f, 0.f, 0.f};
#pragma unroll
  for (int ks = 0; ks < 16; ++ks) {
    const int kb = kbase + ks * 32;
    const int byteB = c * 4096 + (((kb * 2) + g * 16) ^ ((c & 7) << 4));
    half8 bw = *(const half8*)(smem + byteB);  // B-frag: n=q=c, k=8g+j
#pragma unroll
    for (int dt = 0; dt < 4; ++dt) {
      half8 av = *(const half8*)(vp + (size_t)(dt * 16 + c) * 2048 + kb + 8 * g);
      pv[dt] = MFMA16(av, bw, pv[dt]);
    }
  }

  // --- Phase F: cross-wave reduce partials, store concat f16 ---
  __syncthreads();  // all waves done reading W before partials overwrite it
  float* part = (float*)smem + w * 1024;  // [64 d][16 q] per wave
#pragma unroll
  for (int dt = 0; dt < 4; ++dt)
#pragma unroll
    for (int r = 0; r < 4; ++r)
      part[(dt * 16 + 4 * g + r) * 16 + c] = pv[dt][r];
  __syncthreads();

  const int qq = tid & 15, db = (tid >> 4) * 4;
  const float* sp = (const float*)smem;
  union { _Float16 hh[4]; uint2 u; } pk;
#pragma unroll
  for (int i = 0; i < 4; ++i) {
    const int d = db + i;
    pk.hh[i] = (_Float16)(sp[d * 16 + qq] + sp[1024 + d * 16 + qq] +
                          sp[2048 + d * 16 + qq] + sp[3072 + d * 16 + qq]);
  }
  *(uint2*)(concat + (size_t)(b * 2048 + q0 + qq) * 1024 + h * 64 + db) = pk.u;
}

// ---------------------------------------------------------------------------
extern "C" void kernel_launch(void* const* d_in, const int* in_sizes, int n_in,
                              void* d_out, int out_size, void* d_ws, size_t ws_size,
                              hipStream_t stream) {
  const float* Q  = (const float*)d_in[0];
  const float* Kx = (const float*)d_in[1];
  const float* V  = (const float*)d_in[2];
  const float* wq = (const float*)d_in[3];
  const float* bq = (const float*)d_in[4];
  const float* wk = (const float*)d_in[5];
  const float* bk = (const float*)d_in[6];
  const float* wv = (const float*)d_in[7];
  const float* bv = (const float*)d_in[8];
  const float* wo = (const float*)d_in[9];
  const float* bo = (const float*)d_in[10];

  float* out  = (float*)d_out;
  float* wout = out + (size_t)4194304;  // weights [B,H,S,S] after out [B,S,D]

  char* ws = (char*)d_ws;
  const size_t MB = 1024 * 1024;
  _Float16* Xq  = (_Float16*)(ws + 0 * MB);
  _Float16* Xk  = (_Float16*)(ws + 8 * MB);
  _Float16* Xv  = (_Float16*)(ws + 16 * MB);
  _Float16* wqT = (_Float16*)(ws + 24 * MB);
  _Float16* wkT = (_Float16*)(ws + 26 * MB);
  _Float16* wvT = (_Float16*)(ws + 28 * MB);
  _Float16* woT = (_Float16*)(ws + 30 * MB);
  _Float16* qhp = (_Float16*)(ws + 32 * MB);
  _Float16* khp = (_Float16*)(ws + 40 * MB);
  _Float16* vTp = (_Float16*)(ws + 48 * MB);
  _Float16* cat = (_Float16*)(ws + 56 * MB);

  // k0a: converts (4096*1024/8 = 524288 threads each)
  cvt_f16_kernel<<<2048, 256, 0, stream>>>(Q, Xq, 524288);
  cvt_f16_kernel<<<2048, 256, 0, stream>>>(Kx, Xk, 524288);
  cvt_f16_kernel<<<2048, 256, 0, stream>>>(V, Xv, 524288);
  // k0b: weight transposes
  transpose_cvt_kernel<<<dim3(16, 16), 256, 0, stream>>>(wq, wqT);
  transpose_cvt_kernel<<<dim3(16, 16), 256, 0, stream>>>(wk, wkT);
  transpose_cvt_kernel<<<dim3(16, 16), 256, 0, stream>>>(wv, wvT);
  transpose_cvt_kernel<<<dim3(16, 16), 256, 0, stream>>>(wo, woT);
  // k1: projections (M=4096 via grid.y, N=1024 via grid.x, K=1024)
  gemm_f16_kernel<0><<<dim3(8, 32), 256, 0, stream>>>(Xq, wqT, bq, qhp, 1024);
  gemm_f16_kernel<0><<<dim3(8, 32), 256, 0, stream>>>(Xk, wkT, bk, khp, 1024);
  gemm_f16_kernel<1><<<dim3(8, 32), 256, 0, stream>>>(Xv, wvT, bv, vTp, 1024);
  // k2: fused attention
  attn_kernel<<<dim3(128, 16, 2), 256, 0, stream>>>(qhp, khp, vTp, wout, cat);
  // k3: output projection
  gemm_f16_kernel<2><<<dim3(8, 32), 256, 0, stream>>>(cat, woT, bo, out, 1024);
}